// Round 5
// baseline (87.804 us; speedup 1.0000x reference)
//
#include <hip/hip_runtime.h>
#include <math.h>

#define N_ROWS 131072
#define U2_OFF 4096   // floats: Sw = ws[0..4095] (16x256), U2 = ws[4096..4351] (16x16)

// ---------------- stage-1 builder: 8-qubit state, 4 amps/lane ----------------
__device__ __forceinline__ void ry8(float v[4], int lane, int bp, float c, float s) {
  if (bp == 0) {
    float n0 = fmaf(s, v[1], c * v[0]);
    float n1 = fmaf(-s, v[0], c * v[1]);
    float n2 = fmaf(s, v[3], c * v[2]);
    float n3 = fmaf(-s, v[2], c * v[3]);
    v[0] = n0; v[1] = n1; v[2] = n2; v[3] = n3;
  } else if (bp == 1) {
    float n0 = fmaf(s, v[2], c * v[0]);
    float n2 = fmaf(-s, v[0], c * v[2]);
    float n1 = fmaf(s, v[3], c * v[1]);
    float n3 = fmaf(-s, v[1], c * v[3]);
    v[0] = n0; v[1] = n1; v[2] = n2; v[3] = n3;
  } else {
    int lm = 1 << (bp - 2);
    float sgn = ((lane >> (bp - 2)) & 1) ? -s : s;
#pragma unroll
    for (int k = 0; k < 4; ++k) {
      float o = __shfl_xor(v[k], lm);
      v[k] = fmaf(sgn, o, c * v[k]);
    }
  }
}

__device__ __forceinline__ void cnot8(float v[4], int lane, int cb, int tb) {
  if (cb >= 2 && tb >= 2) {
    int lm = 1 << (tb - 2);
    bool hc = (lane >> (cb - 2)) & 1;
#pragma unroll
    for (int k = 0; k < 4; ++k) {
      float o = __shfl_xor(v[k], lm);
      v[k] = hc ? o : v[k];
    }
  } else if (cb >= 2) {
    bool hc = (lane >> (cb - 2)) & 1;
    if (tb == 0) {
      float n0 = hc ? v[1] : v[0], n1 = hc ? v[0] : v[1];
      float n2 = hc ? v[3] : v[2], n3 = hc ? v[2] : v[3];
      v[0] = n0; v[1] = n1; v[2] = n2; v[3] = n3;
    } else {
      float n0 = hc ? v[2] : v[0], n2 = hc ? v[0] : v[2];
      float n1 = hc ? v[3] : v[1], n3 = hc ? v[1] : v[3];
      v[0] = n0; v[1] = n1; v[2] = n2; v[3] = n3;
    }
  } else if (tb >= 2) {
    int lm = 1 << (tb - 2);
#pragma unroll
    for (int k = 0; k < 4; ++k) {
      float o = __shfl_xor(v[k], lm);
      if ((k >> cb) & 1) v[k] = o;
    }
  } else {
    if (cb == 0) { float t = v[1]; v[1] = v[3]; v[3] = t; }
    else         { float t = v[2]; v[2] = v[3]; v[3] = t; }
  }
}

// ---------------- stage-2 builder: full 16-dim state in registers ----------------
template <int BP>
__device__ __forceinline__ void ry16t(float* w, float c, float s) {
#pragma unroll
  for (int i = 0; i < 16; ++i) {
    if (((i >> BP) & 1) == 0) {
      const int j = i | (1 << BP);
      float a = w[i], b = w[j];
      w[i] = fmaf(s, b, c * a);
      w[j] = fmaf(-s, a, c * b);
    }
  }
}
__device__ __forceinline__ void ry16(float* w, int bp, float c, float s) {
  switch (bp) {
    case 0: ry16t<0>(w, c, s); break;
    case 1: ry16t<1>(w, c, s); break;
    case 2: ry16t<2>(w, c, s); break;
    default: ry16t<3>(w, c, s); break;
  }
}
template <int CB, int TB>
__device__ __forceinline__ void cnot16t(float* w) {
#pragma unroll
  for (int i = 0; i < 16; ++i) {
    if (((i >> CB) & 1) == 1 && ((i >> TB) & 1) == 0) {
      const int j = i | (1 << TB);
      float t = w[i]; w[i] = w[j]; w[j] = t;
    }
  }
}
__device__ __forceinline__ void cnot16(float* w, int cb, int tb) {
#define CC(a, b) if (cb == a && tb == b) { cnot16t<a, b>(w); return; }
  CC(0,1) CC(0,2) CC(0,3) CC(1,0) CC(1,2) CC(1,3)
  CC(2,0) CC(2,1) CC(2,3) CC(3,0) CC(3,1) CC(3,2)
#undef CC
}

__global__ void build_states_kernel(const float* __restrict__ thc,
                                    const float* __restrict__ th2,
                                    float* __restrict__ ws) {
  const int blk = blockIdx.x;
  const int lane = threadIdx.x;  // 64 threads
  if (blk < 16) {
    const float* th = thc + blk * 72;
    float v[4] = {0.f, 0.f, 0.f, 0.f};
    if (lane == 0) v[0] = 1.f;
    int p = 0;
    for (int m = 0; m < 8; ++m) {
#pragma unroll
      for (int q = 0; q < 8; ++q) {
        float a = 0.5f * th[p + q];
        ry8(v, lane, 7 - q, cosf(a), sinf(a));
      }
      p += 8;
#pragma unroll
      for (int q = 0; q < 8; ++q) {
        int tgt = (m % 2 == 0) ? ((q + 1) & 7) : ((q + 7) & 7);
        cnot8(v, lane, 7 - q, 7 - tgt);
      }
    }
#pragma unroll
    for (int q = 0; q < 8; ++q) {
      float a = 0.5f * th[p + q];
      ry8(v, lane, 7 - q, cosf(a), sinf(a));
    }
    float4* swv = (float4*)ws;
    swv[blk * 64 + lane] = make_float4(v[0], v[1], v[2], v[3]);
  } else {
    float w[16];
#pragma unroll
    for (int j = 0; j < 16; ++j) w[j] = (j == lane) ? 1.f : 0.f;
    int p = 0;
    for (int m = 0; m < 8; ++m) {
#pragma unroll
      for (int q = 0; q < 4; ++q) {
        float a = 0.5f * th2[p + q];
        ry16(w, 3 - q, cosf(a), sinf(a));
      }
      p += 4;
#pragma unroll
      for (int q = 0; q < 4; ++q) {
        int tgt = (m % 2 == 0) ? ((q + 1) & 3) : ((q + 3) & 3);
        cnot16(w, 3 - q, 3 - tgt);
      }
    }
#pragma unroll
    for (int q = 0; q < 4; ++q) {
      float a = 0.5f * th2[p + q];
      ry16(w, 3 - q, cosf(a), sinf(a));
    }
    if (lane < 16) {
      float* u2 = ws + U2_OFF;
#pragma unroll
      for (int j = 0; j < 16; ++j) u2[lane * 16 + j] = w[j];
    }
  }
}

__device__ __forceinline__ float silu_g(float z) {
  float v = z / (1.f + __expf(-z));
  return isfinite(v) ? v : 0.f;
}

// ---------------- main kernel: LANE OWNS A ROW ----------------
// Block = 4 waves; each wave owns 64 consecutive rows (lane r -> row rb+r).
// x streamed in 32-float chunks: global->LDS coalesced (full 128B lines),
// stored TRANSPOSED (buf[jj][row]) so the compute-side ds_read_b128 is 64
// distinct contiguous addresses (zero broadcast amplification, zero
// conflicts). Sw/U2 are read with wave-uniform indices -> s_load -> SGPR
// operands in v_fma (free). Wave-private buffers -> NO barriers anywhere.
// Epilogue fully per-lane: all 64 lanes active, zero shuffles
// (normalizations folded: U2 orthogonal, final P-norm scale-invariant).
__global__ __launch_bounds__(256, 2) void hadamard_main_kernel(
    const float* __restrict__ x, const float* __restrict__ ws,
    float* __restrict__ out) {
  __shared__ __align__(16) float4 xbuf[4][2][8][64];  // [wave][dbuf][jj][row] = 64 KB

  const int t = threadIdx.x;
  const int w = t >> 6;
  const int lane = t & 63;
  const int rb = blockIdx.x * 256 + w * 64;  // this wave's first row

  const float* __restrict__ sw = ws;  // [16][256], wave-uniform reads
  const float4* __restrict__ xs = (const float4*)x + (size_t)rb * 64;

  float4(*__restrict__ buf)[8][64] = xbuf[w];

  // stage chunk ck (32 floats x 64 rows): 8 insts, each = 8 rows x 128B lines
  float4 st[8];
#define GLOAD(ck)                                                              \
  {                                                                            \
    _Pragma("unroll") for (int i = 0; i < 8; ++i)                              \
        st[i] = xs[(size_t)(i * 8 + (lane >> 3)) * 64 + (ck) * 8 + (lane & 7)];\
  }
#define DSWRITE(b)                                                             \
  {                                                                            \
    _Pragma("unroll") for (int i = 0; i < 8; ++i)                              \
        buf[b][lane & 7][i * 8 + (lane >> 3)] = st[i];                         \
  }

  float z[16];
#pragma unroll
  for (int c = 0; c < 16; ++c) z[c] = 0.f;

  GLOAD(0)
  DSWRITE(0)
  GLOAD(1)

#pragma unroll 1
  for (int ck = 0; ck < 8; ++ck) {
    const int cur = ck & 1;
    if (ck < 7) DSWRITE(cur ^ 1)   // chunk ck+1 (in st) -> other buffer
    if (ck < 6) GLOAD(ck + 2)      // prefetch chunk ck+2 into st
    // compute chunk ck: per lane 32 x-floats vs 16 channels (SGPR operands)
#pragma unroll
    for (int jj = 0; jj < 8; ++jj) {
      const float4 xv = buf[cur][jj][lane];
      const int kb = ck * 32 + jj * 4;
#pragma unroll
      for (int c = 0; c < 16; ++c) {
        z[c] = fmaf(xv.w, sw[c * 256 + kb + 3],
               fmaf(xv.z, sw[c * 256 + kb + 2],
               fmaf(xv.y, sw[c * 256 + kb + 1],
               fmaf(xv.x, sw[c * 256 + kb + 0], z[c]))));
      }
    }
  }

  // ---------------- per-lane epilogue (row = rb + lane) ----------------
  float f[16];
#pragma unroll
  for (int c = 0; c < 16; ++c) f[c] = silu_g(z[c]);

  // T = f @ U2 (unnormalized; U2 orthogonal => scales cancel in P)
  const float* __restrict__ u2 = ws + U2_OFF;
  float T[16];
#pragma unroll
  for (int j = 0; j < 16; ++j) T[j] = 0.f;
#pragma unroll
  for (int c = 0; c < 16; ++c) {
    const float fc = f[c];
#pragma unroll
    for (int j = 0; j < 16; ++j) T[j] = fmaf(fc, u2[c * 16 + j], T[j]);
  }

  // e[t] = T[t]^2 + T[t+8]^2 ; P = e / sum(e)
  float e[8], es = 0.f;
#pragma unroll
  for (int tt = 0; tt < 8; ++tt) {
    e[tt] = fmaf(T[tt], T[tt], T[tt + 8] * T[tt + 8]);
    es += e[tt];
  }
  const float rinv = 1.f / fmaxf(es, 1e-35f);

  float P[8], lp[8];
#pragma unroll
  for (int tt = 0; tt < 8; ++tt) {
    P[tt] = e[tt] * rinv;
    lp[tt] = __logf(fmaxf(P[tt], 1e-12f));
  }

  const int row = rb + lane;
  float4* o0 = (float4*)(out + (size_t)row * 8);
  o0[0] = make_float4(lp[0], lp[1], lp[2], lp[3]);
  o0[1] = make_float4(lp[4], lp[5], lp[6], lp[7]);
  float4* o1 = (float4*)(out + (size_t)N_ROWS * 8 + (size_t)row * 8);
  o1[0] = make_float4(P[0], P[1], P[2], P[3]);
  o1[1] = make_float4(P[4], P[5], P[6], P[7]);
#undef GLOAD
#undef DSWRITE
}

extern "C" void kernel_launch(void* const* d_in, const int* in_sizes, int n_in,
                              void* d_out, int out_size, void* d_ws, size_t ws_size,
                              hipStream_t stream) {
  const float* x = (const float*)d_in[0];
  const float* thc = (const float*)d_in[1];
  const float* th2 = (const float*)d_in[2];
  float* out = (float*)d_out;
  float* ws = (float*)d_ws;

  build_states_kernel<<<17, 64, 0, stream>>>(thc, th2, ws);
  hadamard_main_kernel<<<N_ROWS / 256, 256, 0, stream>>>(x, ws, out);
}

// Round 6
// 55.677 us; speedup vs baseline: 1.5770x; 1.5770x over previous
//
#include <hip/hip_runtime.h>
#include <math.h>

#define N_ROWS 131072
#define U2_OFF 4096   // floats: swT = ws[0..4095] ([256][16]), U2 = ws[4096..4351] (16x16)
#define ZST 20        // z-exchange row stride (floats): (lane*5)%8 distinct -> conflict-free b128

// ---------------- stage-1 builder: 8-qubit state, 4 amps/lane ----------------
__device__ __forceinline__ void ry8(float v[4], int lane, int bp, float c, float s) {
  if (bp == 0) {
    float n0 = fmaf(s, v[1], c * v[0]);
    float n1 = fmaf(-s, v[0], c * v[1]);
    float n2 = fmaf(s, v[3], c * v[2]);
    float n3 = fmaf(-s, v[2], c * v[3]);
    v[0] = n0; v[1] = n1; v[2] = n2; v[3] = n3;
  } else if (bp == 1) {
    float n0 = fmaf(s, v[2], c * v[0]);
    float n2 = fmaf(-s, v[0], c * v[2]);
    float n1 = fmaf(s, v[3], c * v[1]);
    float n3 = fmaf(-s, v[1], c * v[3]);
    v[0] = n0; v[1] = n1; v[2] = n2; v[3] = n3;
  } else {
    int lm = 1 << (bp - 2);
    float sgn = ((lane >> (bp - 2)) & 1) ? -s : s;
#pragma unroll
    for (int k = 0; k < 4; ++k) {
      float o = __shfl_xor(v[k], lm);
      v[k] = fmaf(sgn, o, c * v[k]);
    }
  }
}

__device__ __forceinline__ void cnot8(float v[4], int lane, int cb, int tb) {
  if (cb >= 2 && tb >= 2) {
    int lm = 1 << (tb - 2);
    bool hc = (lane >> (cb - 2)) & 1;
#pragma unroll
    for (int k = 0; k < 4; ++k) {
      float o = __shfl_xor(v[k], lm);
      v[k] = hc ? o : v[k];
    }
  } else if (cb >= 2) {
    bool hc = (lane >> (cb - 2)) & 1;
    if (tb == 0) {
      float n0 = hc ? v[1] : v[0], n1 = hc ? v[0] : v[1];
      float n2 = hc ? v[3] : v[2], n3 = hc ? v[2] : v[3];
      v[0] = n0; v[1] = n1; v[2] = n2; v[3] = n3;
    } else {
      float n0 = hc ? v[2] : v[0], n2 = hc ? v[0] : v[2];
      float n1 = hc ? v[3] : v[1], n3 = hc ? v[1] : v[3];
      v[0] = n0; v[1] = n1; v[2] = n2; v[3] = n3;
    }
  } else if (tb >= 2) {
    int lm = 1 << (tb - 2);
#pragma unroll
    for (int k = 0; k < 4; ++k) {
      float o = __shfl_xor(v[k], lm);
      if ((k >> cb) & 1) v[k] = o;
    }
  } else {
    if (cb == 0) { float t = v[1]; v[1] = v[3]; v[3] = t; }
    else         { float t = v[2]; v[2] = v[3]; v[3] = t; }
  }
}

// ---------------- stage-2 builder: full 16-dim state in registers ----------------
template <int BP>
__device__ __forceinline__ void ry16t(float* w, float c, float s) {
#pragma unroll
  for (int i = 0; i < 16; ++i) {
    if (((i >> BP) & 1) == 0) {
      const int j = i | (1 << BP);
      float a = w[i], b = w[j];
      w[i] = fmaf(s, b, c * a);
      w[j] = fmaf(-s, a, c * b);
    }
  }
}
__device__ __forceinline__ void ry16(float* w, int bp, float c, float s) {
  switch (bp) {
    case 0: ry16t<0>(w, c, s); break;
    case 1: ry16t<1>(w, c, s); break;
    case 2: ry16t<2>(w, c, s); break;
    default: ry16t<3>(w, c, s); break;
  }
}
template <int CB, int TB>
__device__ __forceinline__ void cnot16t(float* w) {
#pragma unroll
  for (int i = 0; i < 16; ++i) {
    if (((i >> CB) & 1) == 1 && ((i >> TB) & 1) == 0) {
      const int j = i | (1 << TB);
      float t = w[i]; w[i] = w[j]; w[j] = t;
    }
  }
}
__device__ __forceinline__ void cnot16(float* w, int cb, int tb) {
#define CC(a, b) if (cb == a && tb == b) { cnot16t<a, b>(w); return; }
  CC(0,1) CC(0,2) CC(0,3) CC(1,0) CC(1,2) CC(1,3)
  CC(2,0) CC(2,1) CC(2,3) CC(3,0) CC(3,1) CC(3,2)
#undef CC
}

__global__ void build_states_kernel(const float* __restrict__ thc,
                                    const float* __restrict__ th2,
                                    float* __restrict__ ws) {
  const int blk = blockIdx.x;
  const int lane = threadIdx.x;  // 64 threads
  if (blk < 16) {
    const float* th = thc + blk * 72;
    float v[4] = {0.f, 0.f, 0.f, 0.f};
    if (lane == 0) v[0] = 1.f;
    int p = 0;
    for (int m = 0; m < 8; ++m) {
#pragma unroll
      for (int q = 0; q < 8; ++q) {
        float a = 0.5f * th[p + q];
        ry8(v, lane, 7 - q, cosf(a), sinf(a));
      }
      p += 8;
#pragma unroll
      for (int q = 0; q < 8; ++q) {
        int tgt = (m % 2 == 0) ? ((q + 1) & 7) : ((q + 7) & 7);
        cnot8(v, lane, 7 - q, 7 - tgt);
      }
    }
#pragma unroll
    for (int q = 0; q < 8; ++q) {
      float a = 0.5f * th[p + q];
      ry8(v, lane, 7 - q, cosf(a), sinf(a));
    }
    // TRANSPOSED store: swT[k][c], k = 4*lane + kk, c = blk
#pragma unroll
    for (int kk = 0; kk < 4; ++kk) ws[(4 * lane + kk) * 16 + blk] = v[kk];
  } else {
    float w[16];
#pragma unroll
    for (int j = 0; j < 16; ++j) w[j] = (j == lane) ? 1.f : 0.f;
    int p = 0;
    for (int m = 0; m < 8; ++m) {
#pragma unroll
      for (int q = 0; q < 4; ++q) {
        float a = 0.5f * th2[p + q];
        ry16(w, 3 - q, cosf(a), sinf(a));
      }
      p += 4;
#pragma unroll
      for (int q = 0; q < 4; ++q) {
        int tgt = (m % 2 == 0) ? ((q + 1) & 3) : ((q + 3) & 3);
        cnot16(w, 3 - q, 3 - tgt);
      }
    }
#pragma unroll
    for (int q = 0; q < 4; ++q) {
      float a = 0.5f * th2[p + q];
      ry16(w, 3 - q, cosf(a), sinf(a));
    }
    if (lane < 16) {
      float* u2 = ws + U2_OFF;
#pragma unroll
      for (int j = 0; j < 16; ++j) u2[lane * 16 + j] = w[j];
    }
  }
}

__device__ __forceinline__ float silu_g(float z) {
  float v = z / (1.f + __expf(-z));
  return isfinite(v) ? v : 0.f;
}

// 16 FMAs: per-lane x element * wave-uniform swT row (s_load -> SGPR operand)
#define FMA16(xe, sp)                                                          \
  {                                                                            \
    const float xe_ = (xe);                                                    \
    const float* __restrict__ s_ = (sp);                                       \
    _Pragma("unroll") for (int c = 0; c < 16; ++c)                             \
        z[c] = fmaf(xe_, s_[c], z[c]);                                         \
  }

// ---------------- main kernel: lane-owns-row, wave-level K-split ----------------
// Block = 4 waves = 2 row-groups x 2 K-halves. Wave (grp,h): rows
// rb+grp*64+lane, k in [h*128, h*128+128). x: per-lane float4 stream (one 64B
// line per lane per iteration). swT[k][0..15]: wave-uniform -> s_load ->
// SGPR operands (free). Partials combined via a tiny padded LDS z-buffer;
// h=1 waves run the per-lane epilogue (normalizations folded out: U2
// orthogonal, final P-norm scale-invariant). No x staging -> no conflicts.
__global__ __launch_bounds__(256, 4) void hadamard_main_kernel(
    const float* __restrict__ x, const float* __restrict__ ws,
    float* __restrict__ out) {
  __shared__ __align__(16) float zb[2][64 * ZST];  // 10.2 KB

  const int t = threadIdx.x;
  const int lane = t & 63;
  const int wu = __builtin_amdgcn_readfirstlane(t >> 6);  // provably uniform
  const int grp = wu >> 1;
  const int h = wu & 1;
  const int row = blockIdx.x * 128 + grp * 64 + lane;

  const float* __restrict__ swT = ws;  // [256][16]
  const float4* __restrict__ xv4 =
      (const float4*)(x + (size_t)row * 256 + h * 128);  // 32 float4s

  float z[16];
#pragma unroll
  for (int c = 0; c < 16; ++c) z[c] = 0.f;

  float4 xq0 = xv4[0], xq1 = xv4[1], xq2 = xv4[2], xq3 = xv4[3];

#pragma unroll 1
  for (int kb = 0; kb < 8; ++kb) {
    // prefetch next 16 k's (one 64B line per lane); clamp keeps last iter in-bounds
    const int pk = (kb < 7 ? kb + 1 : 7) * 4;
    float4 xn0 = xv4[pk], xn1 = xv4[pk + 1], xn2 = xv4[pk + 2], xn3 = xv4[pk + 3];

    const float* __restrict__ sb = swT + (size_t)(h * 128 + kb * 16) * 16;
    FMA16(xq0.x, sb + 0)   FMA16(xq0.y, sb + 16)  FMA16(xq0.z, sb + 32)  FMA16(xq0.w, sb + 48)
    FMA16(xq1.x, sb + 64)  FMA16(xq1.y, sb + 80)  FMA16(xq1.z, sb + 96)  FMA16(xq1.w, sb + 112)
    FMA16(xq2.x, sb + 128) FMA16(xq2.y, sb + 144) FMA16(xq2.z, sb + 160) FMA16(xq2.w, sb + 176)
    FMA16(xq3.x, sb + 192) FMA16(xq3.y, sb + 208) FMA16(xq3.z, sb + 224) FMA16(xq3.w, sb + 240)

    xq0 = xn0; xq1 = xn1; xq2 = xn2; xq3 = xn3;
  }

  // ---- combine K-halves through LDS (padded stride -> conflict-free b128) ----
  if (h == 0) {
    float4* zp = (float4*)&zb[grp][lane * ZST];
    zp[0] = make_float4(z[0], z[1], z[2], z[3]);
    zp[1] = make_float4(z[4], z[5], z[6], z[7]);
    zp[2] = make_float4(z[8], z[9], z[10], z[11]);
    zp[3] = make_float4(z[12], z[13], z[14], z[15]);
  }
  __syncthreads();

  if (h == 1) {
    const float4* zp = (const float4*)&zb[grp][lane * ZST];
    const float4 za = zp[0], zc = zp[1], zd = zp[2], ze = zp[3];
    z[0] += za.x;  z[1] += za.y;  z[2] += za.z;  z[3] += za.w;
    z[4] += zc.x;  z[5] += zc.y;  z[6] += zc.z;  z[7] += zc.w;
    z[8] += zd.x;  z[9] += zd.y;  z[10] += zd.z; z[11] += zd.w;
    z[12] += ze.x; z[13] += ze.y; z[14] += ze.z; z[15] += ze.w;

    // ---------------- per-lane epilogue ----------------
    float f[16];
#pragma unroll
    for (int c = 0; c < 16; ++c) f[c] = silu_g(z[c]);

    // T = f @ U2 (unnormalized; U2 orthogonal => scales cancel in P)
    const float* __restrict__ u2 = ws + U2_OFF;
    float T[16];
#pragma unroll
    for (int j = 0; j < 16; ++j) T[j] = 0.f;
#pragma unroll
    for (int c = 0; c < 16; ++c) {
      const float fc = f[c];
#pragma unroll
      for (int j = 0; j < 16; ++j) T[j] = fmaf(fc, u2[c * 16 + j], T[j]);
    }

    // e[t] = T[t]^2 + T[t+8]^2 ; P = e / sum(e)
    float e[8], es = 0.f;
#pragma unroll
    for (int tt = 0; tt < 8; ++tt) {
      e[tt] = fmaf(T[tt], T[tt], T[tt + 8] * T[tt + 8]);
      es += e[tt];
    }
    const float rinv = 1.f / fmaxf(es, 1e-35f);

    float P[8], lp[8];
#pragma unroll
    for (int tt = 0; tt < 8; ++tt) {
      P[tt] = e[tt] * rinv;
      lp[tt] = __logf(fmaxf(P[tt], 1e-12f));
    }

    float4* o0 = (float4*)(out + (size_t)row * 8);
    o0[0] = make_float4(lp[0], lp[1], lp[2], lp[3]);
    o0[1] = make_float4(lp[4], lp[5], lp[6], lp[7]);
    float4* o1 = (float4*)(out + (size_t)N_ROWS * 8 + (size_t)row * 8);
    o1[0] = make_float4(P[0], P[1], P[2], P[3]);
    o1[1] = make_float4(P[4], P[5], P[6], P[7]);
  }
}

extern "C" void kernel_launch(void* const* d_in, const int* in_sizes, int n_in,
                              void* d_out, int out_size, void* d_ws, size_t ws_size,
                              hipStream_t stream) {
  const float* x = (const float*)d_in[0];
  const float* thc = (const float*)d_in[1];
  const float* th2 = (const float*)d_in[2];
  float* out = (float*)d_out;
  float* ws = (float*)d_ws;

  build_states_kernel<<<17, 64, 0, stream>>>(thc, th2, ws);
  hadamard_main_kernel<<<N_ROWS / 128, 256, 0, stream>>>(x, ws, out);
}